// Round 9
// baseline (13.606 us; speedup 1.0000x reference)
//
#include <hip/hip_runtime.h>

// Soft-DTW (banded, r1=BIG, R0 finite only at j=0) collapses exactly to the
// diagonal distance sum: out = sum_i sqrt(max(||x_i - y_i||^2, 1e-12)).
//
// Single kernel node, TWO-LEVEL fused-atomic combine:
//   level 1: 32 group lines (128B apart), 8 blocks each, one relaxed u64
//            atomicAdd of (fx<<32)|1 per block (fx = 2^-14 fixed partial).
//   level 2: group-last (old lo == 7) adds (grouptot<<32)|1 to the global
//            line; global-last (old lo == 31) writes out from the RETURN
//            VALUE and resets. Integer adds commute -> bitwise-deterministic.
// R8 measured same-line u64 atomics at ~11ns serialized (512 vs 256 blocks:
// +2.9us); tree cuts the root chain 256 -> 32 arrivals (~0.4us tail).
// Init-agnostic: per-line full-word CAS-normalize (counts <= 8/32 can never
// alias >=-threshold poison -> stale CAS can't fire). Lines reset each call.
// R3: memset node +13us. R4: grid.sync +27us. R6->7: fused atomic -11%.

#define TN 4096
#define DFN 256
#define RPB 16
#define NBLK (TN / RPB)  // 256 blocks, 4 waves, 4 rows/wave
#define NGRP 32
#define GSZ (NBLK / NGRP)  // 8 blocks per group
#define FXS 16384.0f       // 2^14 fixed-point scale

#define AGENT __HIP_MEMORY_SCOPE_AGENT

__global__ __launch_bounds__(256) void sdtw_one(const float* __restrict__ x,
                                                const float* __restrict__ y,
                                                unsigned long long* __restrict__ acc,
                                                float* __restrict__ out) {
  const int wave = threadIdx.x >> 6;
  const int lane = threadIdx.x & 63;
  __shared__ float wsum[4];

  // global line = acc[0]; group g line = acc[(1+g)*16]  (128B stride)
  unsigned long long* gacc = acc + (1 + (blockIdx.x & (NGRP - 1))) * 16;

  // Early probes (off the tail critical path). Steady state: counts are 0.
  unsigned long long g0 = 0, v0 = 0;
  if (threadIdx.x == 0) {
    g0 = __hip_atomic_load(gacc, __ATOMIC_RELAXED, AGENT);
    v0 = __hip_atomic_load(acc, __ATOMIC_RELAXED, AGENT);
  }

  // --- per-block diagonal partial: 16 rows, 4 per wave ---
  const int base = blockIdx.x * RPB + wave * 4;
  float d2[4];
#pragma unroll
  for (int r = 0; r < 4; ++r) {
    const float4 xv =
        reinterpret_cast<const float4*>(x)[(base + r) * (DFN / 4) + lane];
    const float4 yv =
        reinterpret_cast<const float4*>(y)[(base + r) * (DFN / 4) + lane];
    const float a = xv.x - yv.x;
    const float b = xv.y - yv.y;
    const float c = xv.z - yv.z;
    const float d = xv.w - yv.w;
    d2[r] = a * a + b * b + c * c + d * d;
  }
  float pacc = 0.0f;
#pragma unroll
  for (int r = 0; r < 4; ++r) {
    float v = d2[r];
#pragma unroll
    for (int s = 32; s >= 1; s >>= 1) v += __shfl_xor(v, s, 64);
    pacc += sqrtf(fmaxf(v, 1e-12f));
  }
  if (lane == 0) wsum[wave] = pacc;
  __syncthreads();

  if (threadIdx.x == 0) {
    const float p = (wsum[0] + wsum[1]) + (wsum[2] + wsum[3]);

    // Init-agnostic normalize (fast path: values already in registers, no CAS)
    unsigned long long v = g0;
    while ((unsigned)(v & 0xFFFFFFFFull) >= (unsigned)GSZ) {
      if (__hip_atomic_compare_exchange_strong(gacc, &v, 0ull, __ATOMIC_RELAXED,
                                               __ATOMIC_RELAXED, AGENT))
        break;
    }
    unsigned long long w = v0;
    while ((unsigned)(w & 0xFFFFFFFFull) >= (unsigned)NGRP) {
      if (__hip_atomic_compare_exchange_strong(acc, &w, 0ull, __ATOMIC_RELAXED,
                                               __ATOMIC_RELAXED, AGENT))
        break;
    }

    const unsigned long long fx =
        (unsigned long long)(unsigned)(p * FXS + 0.5f);
    const unsigned long long old =
        __hip_atomic_fetch_add(gacc, (fx << 32) | 1ull, __ATOMIC_RELAXED, AGENT);

    if ((unsigned)(old & 0xFFFFFFFFull) == (unsigned)(GSZ - 1)) {
      const unsigned long long gtot = (old >> 32) + fx;  // full group sum
      const unsigned long long old2 = __hip_atomic_fetch_add(
          acc, (gtot << 32) | 1ull, __ATOMIC_RELAXED, AGENT);
      if ((unsigned)(old2 & 0xFFFFFFFFull) == (unsigned)(NGRP - 1)) {
        out[0] = (float)((old2 >> 32) + gtot) * (1.0f / FXS);
        __hip_atomic_store(acc, 0ull, __ATOMIC_RELAXED, AGENT);
      }
      __hip_atomic_store(gacc, 0ull, __ATOMIC_RELAXED, AGENT);  // reset group
    }
  }
}

extern "C" void kernel_launch(void* const* d_in, const int* in_sizes, int n_in,
                              void* d_out, int out_size, void* d_ws,
                              size_t ws_size, hipStream_t stream) {
  const float* x = (const float*)d_in[0];
  const float* y = (const float*)d_in[1];
  unsigned long long* acc = (unsigned long long*)d_ws;  // (1+32)*128B used
  float* out = (float*)d_out;

  sdtw_one<<<NBLK, 256, 0, stream>>>(x, y, acc, out);
}

// Round 10
// 10.740 us; speedup vs baseline: 1.2669x; 1.2669x over previous
//
#include <hip/hip_runtime.h>

// Soft-DTW (banded, r1=BIG, R0 finite only at j=0) collapses exactly to the
// diagonal distance sum: out = sum_i sqrt(max(||x_i - y_i||^2, 1e-12)).
//
// SESSION-BEST CONFIG (round 7, 10.48us): single kernel node, 256 blocks,
// 16 rows/block, ONE relaxed u64 atomicAdd per block:
//   addend = (fixed_point_partial << 32) | 1.
// Low word counts blocks (max 256, never carries); high word accumulates the
// 2^-14 fixed-point sum (<= ~1.5e9 < 2^32). Block seeing old-count == NBLK-1
// holds the full sum in the RETURN VALUE -> writes out, resets. Integer adds
// commute -> bitwise-deterministic. Poison/init: low32 >= NBLK -> full-word
// expected-value CAS normalize (any concurrent add invalidates a stale CAS).
//
// Session ledger: R3 memset node +13us; R4 grid.sync +27us; R5/6 fenced
// ticket ~13.3; R7 fused atomic 10.48 (best); R8 512 blocks 13.3; R9
// two-level tree 13.6 (atomic-serialization theory refuted). Floor = fixed
// graph-replay/launch overhead; data movement is only ~1.3us of the budget.

#define TN 4096
#define DFN 256
#define RPB 16
#define NBLK (TN / RPB)  // 256 blocks, 4 waves, 4 rows/wave
#define FXS 16384.0f     // 2^14 fixed-point scale

#define AGENT __HIP_MEMORY_SCOPE_AGENT

__global__ __launch_bounds__(256) void sdtw_one(const float* __restrict__ x,
                                                const float* __restrict__ y,
                                                unsigned long long* __restrict__ acc,
                                                float* __restrict__ out) {
  const int wave = threadIdx.x >> 6;
  const int lane = threadIdx.x & 63;
  __shared__ float wsum[4];

  // Early probe (off the tail critical path). Steady state: low32 < NBLK.
  unsigned long long v0 = 0;
  if (threadIdx.x == 0) v0 = __hip_atomic_load(acc, __ATOMIC_RELAXED, AGENT);

  // --- per-block diagonal partial: 16 rows, 4 per wave ---
  const int base = blockIdx.x * RPB + wave * 4;
  float d2[4];
#pragma unroll
  for (int r = 0; r < 4; ++r) {
    const float4 xv =
        reinterpret_cast<const float4*>(x)[(base + r) * (DFN / 4) + lane];
    const float4 yv =
        reinterpret_cast<const float4*>(y)[(base + r) * (DFN / 4) + lane];
    const float a = xv.x - yv.x;
    const float b = xv.y - yv.y;
    const float c = xv.z - yv.z;
    const float d = xv.w - yv.w;
    d2[r] = a * a + b * b + c * c + d * d;
  }
  float pacc = 0.0f;
#pragma unroll
  for (int r = 0; r < 4; ++r) {
    float v = d2[r];
#pragma unroll
    for (int s = 32; s >= 1; s >>= 1) v += __shfl_xor(v, s, 64);
    pacc += sqrtf(fmaxf(v, 1e-12f));
  }
  if (lane == 0) wsum[wave] = pacc;
  __syncthreads();

  if (threadIdx.x == 0) {
    const float p = (wsum[0] + wsum[1]) + (wsum[2] + wsum[3]);

    // Init-agnostic normalize; fast path costs nothing (v0 in register).
    unsigned long long v = v0;
    while ((unsigned)(v & 0xFFFFFFFFull) >= (unsigned)NBLK) {
      if (__hip_atomic_compare_exchange_strong(acc, &v, 0ull, __ATOMIC_RELAXED,
                                               __ATOMIC_RELAXED, AGENT))
        break;
    }

    const unsigned long long fx = (unsigned long long)(unsigned)(p * FXS + 0.5f);
    const unsigned long long add = (fx << 32) | 1ull;
    const unsigned long long old =
        __hip_atomic_fetch_add(acc, add, __ATOMIC_RELAXED, AGENT);

    if ((unsigned)(old & 0xFFFFFFFFull) == (unsigned)(NBLK - 1)) {
      const unsigned long long tot = (old >> 32) + fx;
      out[0] = (float)tot * (1.0f / FXS);
      __hip_atomic_store(acc, 0ull, __ATOMIC_RELAXED, AGENT);
    }
  }
}

extern "C" void kernel_launch(void* const* d_in, const int* in_sizes, int n_in,
                              void* d_out, int out_size, void* d_ws,
                              size_t ws_size, hipStream_t stream) {
  const float* x = (const float*)d_in[0];
  const float* y = (const float*)d_in[1];
  unsigned long long* acc = (unsigned long long*)d_ws;  // 8 bytes, aligned
  float* out = (float*)d_out;

  sdtw_one<<<NBLK, 256, 0, stream>>>(x, y, acc, out);
}